// Round 7
// baseline (19.105 us; speedup 1.0000x reference)
//
#include <hip/hip_runtime.h>

// Euler characteristic curve of sublevel cubical complex.
// x: [B,C,H,W] f32 -> out: [B,C,RES] f32.
//
// One hist kernel, per (image, 16-row slice) block:
//   - per-vertex (branchless): +1 @ b(v), -1 @ b(v,right), -1 @ b(v,down),
//     +1 @ b(face); bin monotone => bin(max(a,b)) = max(bin(a),bin(b)).
//   - RPT=2 rows/thread; ALL 6 loads (3 float4 + 3 scalar halos) issued
//     upfront -> one vmem stall, max MLP. Small state -> VGPR<=64 ->
//     launch_bounds(256,8) = 8 blocks/CU (100% occupancy), LDS 16KiBx8=128KiB.
//   - hist[bin][lane] int32 LDS, ds_add fire-and-forget (lane columns:
//     only free 2-way bank aliasing; no divergent branches -- R5 lesson).
//   - epilogue: reduce 64 lane-columns, 64-lane shfl inclusive scan
//     (cumsum linear => per-slice scan ok), float atomicAdd into out
//     (integer-valued => exact, order-independent). out zeroed by memset node.

#define HH 128
#define WW 128
#define RESB 64
#define NT 256
#define S 8
#define ROWS (HH / S)    // 16 rows per slice
#define BC 512           // B*C images

__device__ __forceinline__ int binq(float F) {
    // F in [0,1): ceil(F*63) lands in [0,63] -- no clamps needed.
    return (int)ceilf(F * 63.0f);
}

__global__ __launch_bounds__(NT, 8) void ecc_hist(const float* __restrict__ X,
                                                  float* __restrict__ out) {
    __shared__ int hist[RESB * 64];  // [bin][lane], 16 KiB
    const int blk = blockIdx.x;
    const int sl = blk & (S - 1);
    const int bc = blk >> 3;  // blk / S
    const int tid = threadIdx.x;
    const int lane = tid & 63;
    const float* __restrict__ x = X + (size_t)bc * (HH * WW);

    {
        int4* h4 = (int4*)hist;
#pragma unroll
        for (int k = 0; k < 4; ++k) h4[k * NT + tid] = make_int4(0, 0, 0, 0);
    }
    __syncthreads();

    const int col4 = tid & 31;   // which float4 of the row
    const int rg = tid >> 5;     // 0..7 row group
    const int r0 = sl * ROWS + rg * 2;              // rows r0, r0+1 owned
    const int c0 = col4 * 4;
    const int cR = (col4 < 31) ? c0 + 4 : WW - 1;   // right halo col (k=3 masked)
    const int r2 = (r0 + 2 < HH) ? r0 + 2 : HH - 1; // down halo row (masked)

    // Issue all 6 loads upfront: addresses data-independent -> 6 in flight.
    const float4 A = *(const float4*)(x + r0 * WW + c0);
    const float4 Bv = *(const float4*)(x + (r0 + 1) * WW + c0);
    const float4 Cv = *(const float4*)(x + r2 * WW + c0);
    const float Ar = x[r0 * WW + cR];
    const float Br = x[(r0 + 1) * WW + cR];
    const float Cr = x[r2 * WW + cR];

    int ua[5], ub[5], uc[5];
    ua[0] = binq(A.x);  ua[1] = binq(A.y);  ua[2] = binq(A.z);  ua[3] = binq(A.w);  ua[4] = binq(Ar);
    ub[0] = binq(Bv.x); ub[1] = binq(Bv.y); ub[2] = binq(Bv.z); ub[3] = binq(Bv.w); ub[4] = binq(Br);
    uc[0] = binq(Cv.x); uc[1] = binq(Cv.y); uc[2] = binq(Cv.z); uc[3] = binq(Cv.w); uc[4] = binq(Cr);

    // Row r0 always has a down-neighbor (max r0 = 126). Row r0+1: uniform test.
    const int hD1 = (r0 + 1 < HH - 1) ? 1 : 0;

#pragma unroll
    for (int k = 0; k < 4; ++k) {
        const int hR = (k < 3) ? 1 : ((col4 < 31) ? 1 : 0);  // folds for k<3
        {   // row r0 (hD = 1)
            const int u00 = ua[k];
            const int bh = max(u00, ua[k + 1]);
            const int bv = max(u00, ub[k]);
            const int bf = max(bh, max(ub[k], ub[k + 1]));
            atomicAdd(&hist[(u00 << 6) + lane], 1);
            atomicAdd(&hist[(bh << 6) + lane], -hR);
            atomicAdd(&hist[(bv << 6) + lane], -1);
            atomicAdd(&hist[(bf << 6) + lane], hR);
        }
        {   // row r0+1 (hD = hD1)
            const int u00 = ub[k];
            const int bh = max(u00, ub[k + 1]);
            const int bv = max(u00, uc[k]);
            const int bf = max(bh, max(uc[k], uc[k + 1]));
            atomicAdd(&hist[(u00 << 6) + lane], 1);
            atomicAdd(&hist[(bh << 6) + lane], -hR);
            atomicAdd(&hist[(bv << 6) + lane], -hD1);
            atomicAdd(&hist[(bf << 6) + lane], hR & hD1);
        }
    }
    __syncthreads();

    // Reduce over 64 lane-columns: thread (bin = tid&63, q = tid>>6) sums 16,
    // rotated by bin to spread banks.
    const int bin = tid & 63;
    const int q = tid >> 6;
    int ssum = 0;
#pragma unroll
    for (int k = 0; k < 16; ++k) {
        ssum += hist[bin * 64 + q * 16 + ((k + bin) & 15)];
    }
    __syncthreads();
    hist[tid] = ssum;  // partial at [q*64 + bin]
    __syncthreads();
    if (tid < RESB) {
        int vv = hist[tid] + hist[tid + 64] + hist[tid + 128] + hist[tid + 192];
        // Inclusive prefix scan across 64 lanes (= bins): per-slice cumsum.
#pragma unroll
        for (int d = 1; d < 64; d <<= 1) {
            const int up = __shfl_up(vv, d, 64);
            if (tid >= d) vv += up;
        }
        atomicAdd(&out[bc * RESB + tid], (float)vv);  // exact: integer-valued
    }
}

extern "C" void kernel_launch(void* const* d_in, const int* in_sizes, int n_in,
                              void* d_out, int out_size, void* d_ws, size_t ws_size,
                              hipStream_t stream) {
    const float* x = (const float*)d_in[0];
    float* out = (float*)d_out;
    hipMemsetAsync(out, 0, (size_t)BC * RESB * sizeof(float), stream);
    ecc_hist<<<BC * S, NT, 0, stream>>>(x, out);
}

// Round 8
// 18.154 us; speedup vs baseline: 1.0524x; 1.0524x over previous
//
#include <hip/hip_runtime.h>

// Euler characteristic curve of sublevel cubical complex.
// x: [B,C,H,W] f32 -> out: [B,C,RES] f32.
//
// R4 structure (proven 15.1us) + fused scan tail (single experimental change):
//   - per (image, 32-row slice) block; rolling RPT=4 rows/thread;
//     branchless 4-atomic per vertex into hist[bin][lane] int32 LDS
//     (ds_add fire-and-forget; lane columns -> free 2-way bank aliasing);
//     edge/face bins via integer max (bin monotone).
//   - epilogue: reduce 64 lane-columns, 64-lane shfl inclusive scan
//     (cumsum linear => per-slice scan ok), float atomicAdd into out
//     (integer-valued < 2^24 => exact, order-independent).
//     out zeroed by a memset node; no ws, no second kernel.
//   - launch_bounds(256,5): VGPR cap 102 (R4-proven; (256,8)'s 64-cap spills
//     cost 7us in R2/R6).

#define BB 32
#define CC 16
#define HH 128
#define WW 128
#define RESB 64
#define NT 256
#define S 4
#define ROWS (HH / S)    // 32 rows per slice
#define RPT (ROWS / 8)   // 4 consecutive rows per thread
#define BC (BB * CC)

__device__ __forceinline__ int binq(float F) {
    // F in [0,1): ceil(F*63) lands in [0,63] -- no clamps needed.
    return (int)ceilf(F * 63.0f);
}

__global__ __launch_bounds__(NT, 5) void ecc_hist(const float* __restrict__ X,
                                                  float* __restrict__ out) {
    __shared__ int hist[RESB * 64];  // [bin][lane], 16 KiB
    const int blk = blockIdx.x;
    const int sl = blk & (S - 1);
    const int bc = blk >> 2;  // blk / S
    const int tid = threadIdx.x;
    const int lane = tid & 63;
    const float* __restrict__ x = X + (size_t)bc * (HH * WW);

    {
        int4* h4 = (int4*)hist;
#pragma unroll
        for (int k = 0; k < 4; ++k) h4[k * NT + tid] = make_int4(0, 0, 0, 0);
    }
    __syncthreads();

    const int col4 = tid & 31;   // which float4 of the row
    const int tr = tid >> 5;     // 0..7 thread-row group
    const int r0 = sl * ROWS + tr * RPT;
    const int c0 = col4 * 4;
    const int cR = (col4 < 31) ? c0 + 4 : WW - 1;  // right halo col (k=3 masked)

    int u[5], v[5];
    {
        const float4 a = *(const float4*)(x + r0 * WW + c0);
        const float aR = x[r0 * WW + cR];
        u[0] = binq(a.x); u[1] = binq(a.y); u[2] = binq(a.z); u[3] = binq(a.w); u[4] = binq(aR);
    }

#pragma unroll
    for (int dr = 0; dr < RPT; ++dr) {
        const int r = r0 + dr;
        const int hD = (r < HH - 1) ? 1 : 0;
        const int r1 = hD ? r + 1 : r;  // last image row: dup (contribs masked)
        {
            const float4 b = *(const float4*)(x + r1 * WW + c0);
            const float bR = x[r1 * WW + cR];
            v[0] = binq(b.x); v[1] = binq(b.y); v[2] = binq(b.z); v[3] = binq(b.w); v[4] = binq(bR);
        }
#pragma unroll
        for (int k = 0; k < 4; ++k) {
            const int hR = (k < 3) ? 1 : ((col4 < 31) ? 1 : 0);  // folds for k<3
            const int u00 = u[k];
            const int bh  = max(u00, u[k + 1]);
            const int bvv = max(u00, v[k]);
            const int bf  = max(bh, max(v[k], v[k + 1]));
            atomicAdd(&hist[(u00 << 6) + lane], 1);               // vertex +
            atomicAdd(&hist[(bh  << 6) + lane], -hR);             // h-edge -
            atomicAdd(&hist[(bvv << 6) + lane], -hD);             // v-edge -
            atomicAdd(&hist[(bf  << 6) + lane], hR & hD);         // face  +
        }
#pragma unroll
        for (int k = 0; k < 5; ++k) u[k] = v[k];
    }
    __syncthreads();

    // Reduce over 64 lane-columns: thread (bin = tid&63, q = tid>>6) sums 16,
    // rotated by bin to spread banks.
    const int bin = tid & 63;
    const int q = tid >> 6;
    int ssum = 0;
#pragma unroll
    for (int k = 0; k < 16; ++k) {
        ssum += hist[bin * 64 + q * 16 + ((k + bin) & 15)];
    }
    __syncthreads();
    hist[tid] = ssum;  // partial at [q*64 + bin]
    __syncthreads();
    if (tid < RESB) {
        int vv = hist[tid] + hist[tid + 64] + hist[tid + 128] + hist[tid + 192];
        // Inclusive prefix scan across 64 lanes (= bins): per-slice cumsum.
#pragma unroll
        for (int d = 1; d < 64; d <<= 1) {
            const int up = __shfl_up(vv, d, 64);
            if (tid >= d) vv += up;
        }
        atomicAdd(&out[bc * RESB + tid], (float)vv);  // exact: integer-valued
    }
}

extern "C" void kernel_launch(void* const* d_in, const int* in_sizes, int n_in,
                              void* d_out, int out_size, void* d_ws, size_t ws_size,
                              hipStream_t stream) {
    const float* x = (const float*)d_in[0];
    float* out = (float*)d_out;
    hipMemsetAsync(out, 0, (size_t)BC * RESB * sizeof(float), stream);
    ecc_hist<<<BC * S, NT, 0, stream>>>(x, out);
}

// Round 9
// 14.881 us; speedup vs baseline: 1.2839x; 1.2199x over previous
//
#include <hip/hip_runtime.h>

// Euler characteristic curve of sublevel cubical complex.
// x: [B,C,H,W] f32 -> out: [B,C,RES] f32.
//
// R4 structure (proven best) + single change: ALL 10 loads hoisted upfront.
//   - per (image, 32-row slice) block; 4 rows/thread; 5 float4 + 5 halo
//     scalars issued back-to-back (address-independent) -> one vmem-latency
//     stall instead of four serial round-trips.
//   - branchless 4-atomic per vertex into hist[bin][lane] int32 LDS
//     (ds_add fire-and-forget; lane columns -> free 2-way bank aliasing);
//     edge/face bins via integer max (bin monotone: bin(max)=max(bin)).
//   - kernel 2: per image, sum 4 slice partials + 64-lane shfl scan -> out.
//   - launch_bounds(256,5): VGPR cap 102 ((256,8)'s 64-cap spills cost 7us).

#define BB 32
#define CC 16
#define HH 128
#define WW 128
#define RESB 64
#define NT 256
#define S 4
#define ROWS (HH / S)    // 32 rows per slice
#define RPT 4            // rows per thread
#define BC (BB * CC)

__device__ __forceinline__ int binq(float F) {
    // F in [0,1): ceil(F*63) lands in [0,63] -- no clamps needed.
    return (int)ceilf(F * 63.0f);
}

__global__ __launch_bounds__(NT, 5) void ecc_hist(const float* __restrict__ X,
                                                  int* __restrict__ ws) {
    __shared__ int hist[RESB * 64];  // [bin][lane], 16 KiB
    const int blk = blockIdx.x;
    const int sl = blk & (S - 1);
    const int bc = blk >> 2;  // blk / S
    const int tid = threadIdx.x;
    const int lane = tid & 63;
    const float* __restrict__ x = X + (size_t)bc * (HH * WW);

    {
        int4* h4 = (int4*)hist;
#pragma unroll
        for (int k = 0; k < 4; ++k) h4[k * NT + tid] = make_int4(0, 0, 0, 0);
    }
    __syncthreads();

    const int col4 = tid & 31;   // which float4 of the row
    const int tr = tid >> 5;     // 0..7 thread-row group
    const int r0 = sl * ROWS + tr * RPT;
    const int c0 = col4 * 4;
    const int cR = (col4 < 31) ? c0 + 4 : WW - 1;     // right halo col (k=3 masked)
    const int r4c = (r0 + 4 < HH) ? r0 + 4 : HH - 1;  // down halo row (clamped; masked)

    // All 10 loads upfront -- address-independent, maximal MLP.
    const float4 R0 = *(const float4*)(x + (r0 + 0) * WW + c0);
    const float4 R1 = *(const float4*)(x + (r0 + 1) * WW + c0);
    const float4 R2 = *(const float4*)(x + (r0 + 2) * WW + c0);
    const float4 R3 = *(const float4*)(x + (r0 + 3) * WW + c0);
    const float4 R4v = *(const float4*)(x + r4c * WW + c0);
    const float H0 = x[(r0 + 0) * WW + cR];
    const float H1 = x[(r0 + 1) * WW + cR];
    const float H2 = x[(r0 + 2) * WW + cR];
    const float H3 = x[(r0 + 3) * WW + cR];
    const float H4 = x[r4c * WW + cR];

    int bn[5][5];
    bn[0][0] = binq(R0.x); bn[0][1] = binq(R0.y); bn[0][2] = binq(R0.z); bn[0][3] = binq(R0.w); bn[0][4] = binq(H0);
    bn[1][0] = binq(R1.x); bn[1][1] = binq(R1.y); bn[1][2] = binq(R1.z); bn[1][3] = binq(R1.w); bn[1][4] = binq(H1);
    bn[2][0] = binq(R2.x); bn[2][1] = binq(R2.y); bn[2][2] = binq(R2.z); bn[2][3] = binq(R2.w); bn[2][4] = binq(H2);
    bn[3][0] = binq(R3.x); bn[3][1] = binq(R3.y); bn[3][2] = binq(R3.z); bn[3][3] = binq(R3.w); bn[3][4] = binq(H3);
    bn[4][0] = binq(R4v.x); bn[4][1] = binq(R4v.y); bn[4][2] = binq(R4v.z); bn[4][3] = binq(R4v.w); bn[4][4] = binq(H4);

    // Only the last owned row (r0+3) can touch the image boundary (r0+3 = 127).
    const int hD3 = (r0 + 3 < HH - 1) ? 1 : 0;

#pragma unroll
    for (int dr = 0; dr < RPT; ++dr) {
        const int hD = (dr < 3) ? 1 : hD3;  // compile-time 1 for dr<3
#pragma unroll
        for (int k = 0; k < 4; ++k) {
            const int hR = (k < 3) ? 1 : ((col4 < 31) ? 1 : 0);  // folds for k<3
            const int u00 = bn[dr][k];
            const int bh  = max(u00, bn[dr][k + 1]);
            const int bvv = max(u00, bn[dr + 1][k]);
            const int bf  = max(bh, max(bn[dr + 1][k], bn[dr + 1][k + 1]));
            atomicAdd(&hist[(u00 << 6) + lane], 1);          // vertex +
            atomicAdd(&hist[(bh  << 6) + lane], -hR);        // h-edge -
            atomicAdd(&hist[(bvv << 6) + lane], -hD);        // v-edge -
            atomicAdd(&hist[(bf  << 6) + lane], hR & hD);    // face  +
        }
    }
    __syncthreads();

    // Reduce over 64 lane-columns: thread (bin = tid&63, q = tid>>6) sums 16,
    // rotated by bin to spread banks.
    const int bin = tid & 63;
    const int q = tid >> 6;
    int ssum = 0;
#pragma unroll
    for (int k = 0; k < 16; ++k) {
        ssum += hist[bin * 64 + q * 16 + ((k + bin) & 15)];
    }
    __syncthreads();
    hist[tid] = ssum;  // partial at [q*64 + bin]
    __syncthreads();
    if (tid < RESB) {
        ws[blk * RESB + tid] = hist[tid] + hist[tid + 64] + hist[tid + 128] + hist[tid + 192];
    }
}

__global__ __launch_bounds__(64) void ecc_scan(const int* __restrict__ ws,
                                               float* __restrict__ out) {
    const int bc = blockIdx.x;
    const int b = threadIdx.x;  // bin
    int v = 0;
#pragma unroll
    for (int si = 0; si < S; ++si) v += ws[(bc * S + si) * RESB + b];
    // Inclusive prefix scan over 64 lanes (= 64 bins) -> cumsum.
#pragma unroll
    for (int d = 1; d < 64; d <<= 1) {
        const int up = __shfl_up(v, d, 64);
        if (b >= d) v += up;
    }
    out[bc * RESB + b] = (float)v;
}

extern "C" void kernel_launch(void* const* d_in, const int* in_sizes, int n_in,
                              void* d_out, int out_size, void* d_ws, size_t ws_size,
                              hipStream_t stream) {
    const float* x = (const float*)d_in[0];
    float* out = (float*)d_out;
    int* ws = (int*)d_ws;  // BC*S*RESB ints = 512 KiB
    ecc_hist<<<BC * S, NT, 0, stream>>>(x, ws);
    ecc_scan<<<BC, 64, 0, stream>>>(ws, out);
}

// Round 10
// 13.810 us; speedup vs baseline: 1.3834x; 1.0776x over previous
//
#include <hip/hip_runtime.h>

// Euler characteristic curve of sublevel cubical complex.
// x: [B,C,H,W] f32 -> out: [B,C,RES] f32.
//
// R8 structure + LDS-op reduction (hist is LDS-pipe-bound at CU level):
//   - hist shrunk to 32 lane-columns (8 KiB): main-loop ds_add cost unchanged
//     (2 lanes/bank = free aliasing or same-addr serialize, both ~2cyc),
//     epilogue reduce + zero-init halve.
//   - reduce rotation made fully conflict-free: col (q*8+bin+k)&31 -> 64
//     lanes cover all 32 banks (2-way = free), vs old 4-way pattern.
//   - per (image, 32-row slice) block; 4 rows/thread; all 10 loads hoisted
//     (5 float4 + 5 halo scalars) -> single vmem-latency stall, max MLP.
//   - branchless 4-atomic per vertex; edge/face bins via integer max
//     (bin monotone: bin(max)=max(bin)).
//   - kernel 2: per image, sum 4 slice partials + 64-lane shfl scan -> out.
//   - launch_bounds(256,5): VGPR cap 102 ((256,8)'s 64-cap spills cost 7us).

#define BB 32
#define CC 16
#define HH 128
#define WW 128
#define RESB 64
#define NT 256
#define S 4
#define ROWS (HH / S)    // 32 rows per slice
#define RPT 4            // rows per thread
#define BC (BB * CC)

__device__ __forceinline__ int binq(float F) {
    // F in [0,1): ceil(F*63) lands in [0,63] -- no clamps needed.
    return (int)ceilf(F * 63.0f);
}

__global__ __launch_bounds__(NT, 5) void ecc_hist(const float* __restrict__ X,
                                                  int* __restrict__ ws) {
    __shared__ int hist[RESB * 32];  // [bin][col], 8 KiB
    const int blk = blockIdx.x;
    const int sl = blk & (S - 1);
    const int bc = blk >> 2;  // blk / S
    const int tid = threadIdx.x;
    const int ln = tid & 31;  // lane column
    const float* __restrict__ x = X + (size_t)bc * (HH * WW);

    {
        int4* h4 = (int4*)hist;
        h4[tid] = make_int4(0, 0, 0, 0);
        h4[tid + NT] = make_int4(0, 0, 0, 0);
    }
    __syncthreads();

    const int col4 = tid & 31;   // which float4 of the row
    const int tr = tid >> 5;     // 0..7 thread-row group
    const int r0 = sl * ROWS + tr * RPT;
    const int c0 = col4 * 4;
    const int cR = (col4 < 31) ? c0 + 4 : WW - 1;     // right halo col (k=3 masked)
    const int r4c = (r0 + 4 < HH) ? r0 + 4 : HH - 1;  // down halo row (clamped; masked)

    // All 10 loads upfront -- address-independent, maximal MLP.
    const float4 R0 = *(const float4*)(x + (r0 + 0) * WW + c0);
    const float4 R1 = *(const float4*)(x + (r0 + 1) * WW + c0);
    const float4 R2 = *(const float4*)(x + (r0 + 2) * WW + c0);
    const float4 R3 = *(const float4*)(x + (r0 + 3) * WW + c0);
    const float4 R4v = *(const float4*)(x + r4c * WW + c0);
    const float H0 = x[(r0 + 0) * WW + cR];
    const float H1 = x[(r0 + 1) * WW + cR];
    const float H2 = x[(r0 + 2) * WW + cR];
    const float H3 = x[(r0 + 3) * WW + cR];
    const float H4 = x[r4c * WW + cR];

    int bn[5][5];
    bn[0][0] = binq(R0.x); bn[0][1] = binq(R0.y); bn[0][2] = binq(R0.z); bn[0][3] = binq(R0.w); bn[0][4] = binq(H0);
    bn[1][0] = binq(R1.x); bn[1][1] = binq(R1.y); bn[1][2] = binq(R1.z); bn[1][3] = binq(R1.w); bn[1][4] = binq(H1);
    bn[2][0] = binq(R2.x); bn[2][1] = binq(R2.y); bn[2][2] = binq(R2.z); bn[2][3] = binq(R2.w); bn[2][4] = binq(H2);
    bn[3][0] = binq(R3.x); bn[3][1] = binq(R3.y); bn[3][2] = binq(R3.z); bn[3][3] = binq(R3.w); bn[3][4] = binq(H3);
    bn[4][0] = binq(R4v.x); bn[4][1] = binq(R4v.y); bn[4][2] = binq(R4v.z); bn[4][3] = binq(R4v.w); bn[4][4] = binq(H4);

    // Only the last owned row (r0+3) can touch the image boundary (r0+3 = 127).
    const int hD3 = (r0 + 3 < HH - 1) ? 1 : 0;

#pragma unroll
    for (int dr = 0; dr < RPT; ++dr) {
        const int hD = (dr < 3) ? 1 : hD3;  // compile-time 1 for dr<3
#pragma unroll
        for (int k = 0; k < 4; ++k) {
            const int hR = (k < 3) ? 1 : ((col4 < 31) ? 1 : 0);  // folds for k<3
            const int u00 = bn[dr][k];
            const int bh  = max(u00, bn[dr][k + 1]);
            const int bvv = max(u00, bn[dr + 1][k]);
            const int bf  = max(bh, max(bn[dr + 1][k], bn[dr + 1][k + 1]));
            atomicAdd(&hist[(u00 << 5) + ln], 1);          // vertex +
            atomicAdd(&hist[(bh  << 5) + ln], -hR);        // h-edge -
            atomicAdd(&hist[(bvv << 5) + ln], -hD);        // v-edge -
            atomicAdd(&hist[(bf  << 5) + ln], hR & hD);    // face  +
        }
    }
    __syncthreads();

    // Reduce over 32 columns: thread (bin = tid&63, q = tid>>6) sums 8,
    // full rotation -> 64 lanes cover all 32 banks (2-way = free).
    const int bin = tid & 63;
    const int q = tid >> 6;
    int ssum = 0;
#pragma unroll
    for (int k = 0; k < 8; ++k) {
        ssum += hist[(bin << 5) + ((q * 8 + bin + k) & 31)];
    }
    __syncthreads();
    hist[tid] = ssum;  // partial at [q*64 + bin]
    __syncthreads();
    if (tid < RESB) {
        ws[blk * RESB + tid] = hist[tid] + hist[tid + 64] + hist[tid + 128] + hist[tid + 192];
    }
}

__global__ __launch_bounds__(64) void ecc_scan(const int* __restrict__ ws,
                                               float* __restrict__ out) {
    const int bc = blockIdx.x;
    const int b = threadIdx.x;  // bin
    int v = 0;
#pragma unroll
    for (int si = 0; si < S; ++si) v += ws[(bc * S + si) * RESB + b];
    // Inclusive prefix scan over 64 lanes (= 64 bins) -> cumsum.
#pragma unroll
    for (int d = 1; d < 64; d <<= 1) {
        const int up = __shfl_up(v, d, 64);
        if (b >= d) v += up;
    }
    out[bc * RESB + b] = (float)v;
}

extern "C" void kernel_launch(void* const* d_in, const int* in_sizes, int n_in,
                              void* d_out, int out_size, void* d_ws, size_t ws_size,
                              hipStream_t stream) {
    const float* x = (const float*)d_in[0];
    float* out = (float*)d_out;
    int* ws = (int*)d_ws;  // BC*S*RESB ints = 512 KiB
    ecc_hist<<<BC * S, NT, 0, stream>>>(x, ws);
    ecc_scan<<<BC, 64, 0, stream>>>(ws, out);
}